// Round 15
// baseline (232.205 us; speedup 1.0000x reference)
//
#include <hip/hip_runtime.h>
#include <hip/hip_bf16.h>

// ---------------------------------------------------------------------------
// AttentionBlock: B=8, L=1024, C=1024, H=8, ch=128.
// fp32 I/O, bf16 MFMA internal.
// R8: scattered 2B global stores amplify HBM writes ~10x.
// R13/R14: XCD band swizzle -> 49MB fetch.  R15: 2-deep counted-vmcnt
//      pipeline = 878 TF 2-barrier ceiling.  R16: phase port w/ MORE
//      barriers regressed.  R20: scalar ds-scatter V too slow.
// R22: transpose_head ELIMINATED via W layout [g][d][s7][off].
// R23/24: attn QBLK=256 (232.2us).  R25: attn KVBLK=128 (225.4us best).
// R26: gemm_qkv 3-BUFFER rotation: stage t+2 into buf((t+2)%3) at top of
//      iter (its readers provably done at prior barrier) -> mid-iteration
//      lgkm+barrier DELETED: 1 barrier/K-tile (was 2).  256x128 tile,
//      512 thr (R12 wave map + stage geometry), 144KB LDS, grid 768,
//      R14 band swizzle.  Ledger: 12 outstanding, vmcnt(6) steady.
// ---------------------------------------------------------------------------

typedef __attribute__((ext_vector_type(8))) short short8;
typedef __attribute__((ext_vector_type(4))) float f32x4;

#define QK_SCALE 0.29730177875068026f  // 128^-0.25

__device__ __forceinline__ float bf2f(ushort u) {
    union { float f; unsigned int i; } c; c.i = ((unsigned int)u) << 16; return c.f;
}
__device__ __forceinline__ ushort f2bf(float f) {
    union { float f; unsigned int i; } c; c.f = f;
    unsigned int x = c.i;
    return (ushort)((x + 0x7FFFu + ((x >> 16) & 1u)) >> 16);  // RNE
}

// async 16B global->LDS (m97; LDS dest must be wave-uniform base + lane*16)
__device__ __forceinline__ void gload_lds16(const ushort* g, ushort* l) {
    __builtin_amdgcn_global_load_lds(
        (const __attribute__((address_space(1))) unsigned int*)g,
        (__attribute__((address_space(3))) unsigned int*)l, 16, 0, 0);
}

// ---------------------------------------------------------------------------
// Prep kernel: LN row-per-wave (blocks 0..2047, 4 rows/block, no barriers)
// + w_qkv transpose tiles (2048..5119) + w_out transpose (5120..6143).
// ---------------------------------------------------------------------------
__global__ __launch_bounds__(256) void prep_kernel(
    const float* __restrict__ x, const float* __restrict__ g,
    const float* __restrict__ b, ushort* __restrict__ xn,
    const float* __restrict__ w_qkv, ushort* __restrict__ wqkvT,
    const float* __restrict__ w_out, ushort* __restrict__ woutT) {
    __shared__ ushort t[32][33];
    int bid = blockIdx.x;
    int tid = threadIdx.x;
    if (bid < 2048) {
        // ---- LayerNorm: one row per wave ----
        int w = tid >> 6, lane = tid & 63;
        int row = bid * 4 + w;
        const float* xr = x + (size_t)row * 1024;
        float v[4][4];
        float s1 = 0.f, s2 = 0.f;
#pragma unroll
        for (int j = 0; j < 4; j++) {
            float4 t4 = *(const float4*)(xr + lane * 4 + j * 256);
            v[j][0] = t4.x; v[j][1] = t4.y; v[j][2] = t4.z; v[j][3] = t4.w;
#pragma unroll
            for (int e = 0; e < 4; e++) { s1 += v[j][e]; s2 += v[j][e] * v[j][e]; }
        }
#pragma unroll
        for (int m = 32; m >= 1; m >>= 1) { s1 += __shfl_xor(s1, m); s2 += __shfl_xor(s2, m); }
        float mu = s1 * (1.0f / 1024.0f);
        float var = s2 * (1.0f / 1024.0f) - mu * mu;
        float rs = rsqrtf(var + 1e-5f);
#pragma unroll
        for (int j = 0; j < 4; j++) {
            int c0 = lane * 4 + j * 256;
            float4 gg = *(const float4*)(g + c0);
            float4 bb = *(const float4*)(b + c0);
            float gA[4] = {gg.x, gg.y, gg.z, gg.w};
            float bA[4] = {bb.x, bb.y, bb.z, bb.w};
            ushort o[4];
#pragma unroll
            for (int e = 0; e < 4; e++) o[e] = f2bf((v[j][e] - mu) * rs * gA[e] + bA[e]);
            uint2 pk;
            pk.x = (uint)o[0] | ((uint)o[1] << 16);
            pk.y = (uint)o[2] | ((uint)o[3] << 16);
            *(uint2*)(xn + (size_t)row * 1024 + c0) = pk;
        }
    } else {
        // ---- weight transpose tile ----
        const float* in; ushort* out; int R, Cc, bx, by;
        if (bid < 5120) {
            int tt = bid - 2048;
            in = w_qkv; out = wqkvT; R = 1024; Cc = 3072;
            bx = (tt % 96) * 32; by = (tt / 96) * 32;
        } else {
            int tt = bid - 5120;
            in = w_out; out = woutT; R = 1024; Cc = 1024;
            bx = (tt % 32) * 32; by = (tt / 32) * 32;
        }
        int tx = tid & 31, ty = tid >> 5;
#pragma unroll
        for (int j = 0; j < 32; j += 8)
            t[ty + j][tx] = f2bf(in[(size_t)(by + ty + j) * Cc + bx + tx]);
        __syncthreads();
#pragma unroll
        for (int j = 0; j < 32; j += 8)
            out[(size_t)(bx + ty + j) * R + by + tx] = t[tx][ty + j];
    }
}

// ---------------------------------------------------------------------------
// QKV GEMM R26: C[8192,3072] = A[8192,1024] @ Bt[3072,1024]^T.
// 256x128 tile, BK=64, 512 thr = 8 waves (4M x 2N, 64x64 out per wave).
// LDS 144 KB: AS[3][256x64] + BS[3][128x64], 3-buffer rotation.
// ONE barrier per K-tile:
//   iter t: {read 16 frags from buf(t%3); stage t+2 -> buf((t+2)%3);
//            MFMA kk0+kk1 (setprio); vmcnt(6); barrier}
// Stage-at-top is safe: buf((t+2)%3)'s last readers (iter t-1) completed
// their ds_reads before their MFMAs, hence before the prior barrier.
// Ledger: prologue 12 outstanding -> vmcnt(6); steady vmcnt(6) drains the
// oldest 6 (tile t+1); t=14 vmcnt(0); t=15 bare.
// Grid 768 = 3 exact CU waves; XCD x owns M-tiles [4x,4x+4) (2MB A band).
// Q,K epilogue scaled row-major; V epilogue W[g][d][s7][off] (g=row>>7).
// ---------------------------------------------------------------------------
__device__ __forceinline__ void stage6q(const ushort* __restrict__ Ab,
                                        const ushort* __restrict__ Bb, int t2,
                                        ushort* AsD, ushort* BsD, int tid) {
    const ushort* As_src = Ab + t2 * 64;
    const ushort* Bs_src = Bb + t2 * 64;
#pragma unroll
    for (int i = 0; i < 4; i++) {
        int lin = i * 512 + tid;             // 0..2047: A-tile 16B chunk id
        int r = lin >> 3, p = lin & 7;
        int l = p ^ (r & 7);
        gload_lds16(As_src + (size_t)r * 1024 + l * 8, &AsD[lin * 8]);
    }
#pragma unroll
    for (int i = 0; i < 2; i++) {
        int lin = i * 512 + tid;             // 0..1023: B-tile chunk id
        int r = lin >> 3, p = lin & 7;
        int l = p ^ (r & 7);
        gload_lds16(Bs_src + (size_t)r * 1024 + l * 8, &BsD[lin * 8]);
    }
}

__global__ __launch_bounds__(512) void gemm_qkv(
    const ushort* __restrict__ A, const ushort* __restrict__ Bt,
    const float* __restrict__ bias, ushort* __restrict__ out0,
    ushort* __restrict__ out1, ushort* __restrict__ wv) {
    __shared__ __align__(16) ushort AS[3][256 * 64];  // 96 KB
    __shared__ __align__(16) ushort BS[3][128 * 64];  // 48 KB

    int tid = threadIdx.x;
    int lane = tid & 63, w = tid >> 6;       // 8 waves
    int l15 = lane & 15, q4 = lane >> 4;
    int wrM = (w >> 1) * 64;                 // wave M offset: 0/64/128/192
    int wcN = (w & 1) * 64;                  // wave N offset: 0/64

    // R14-proven band swizzle: XCD x owns M-tiles 4x..4x+3, N-fastest.
    int bid = blockIdx.x;
    int xcd = bid & 7;
    int ib = bid >> 3;                       // 0..95
    int by = xcd * 4 + (ib & 3);             // M-tile 0..31
    int bx = ib >> 2;                        // N-tile 0..23
    int rowBase = by * 256, colBase = bx * 128;

    const ushort* Ab = A + (size_t)rowBase * 1024;
    const ushort* Bb = Bt + (size_t)colBase * 1024;

    f32x4 acc[4][4];
    f32x4 zero = {0.f, 0.f, 0.f, 0.f};
#pragma unroll
    for (int mi = 0; mi < 4; mi++)
#pragma unroll
        for (int ni = 0; ni < 4; ni++) acc[mi][ni] = zero;

    // prologue: stage t0->buf0, t1->buf1 (12 outstanding); drain t0.
    stage6q(Ab, Bb, 0, &AS[0][0], &BS[0][0], tid);
    stage6q(Ab, Bb, 1, &AS[1][0], &BS[1][0], tid);
    asm volatile("s_waitcnt vmcnt(6)" ::: "memory");
    __builtin_amdgcn_s_barrier();

    ushort* rA = &AS[0][0]; ushort* rB = &BS[0][0];   // read  (tile t)
    ushort* nA = &AS[1][0]; ushort* nB = &BS[1][0];   // next  (tile t+1)
    ushort* sA = &AS[2][0]; ushort* sB = &BS[2][0];   // stage (tile t+2)

    for (int t = 0; t < 16; ++t) {
        // ---- read all 16 fragments of this K-tile into registers ----
        short8 aF[4][2], bF[4][2];
#pragma unroll
        for (int kk = 0; kk < 2; kk++) {
#pragma unroll
            for (int mi = 0; mi < 4; mi++) {
                int r = wrM + mi * 16 + l15;
                aF[mi][kk] = *(const short8*)&rA[r * 64 + ((kk * 4 + q4) ^ (r & 7)) * 8];
            }
#pragma unroll
            for (int ni = 0; ni < 4; ni++) {
                int r = wcN + ni * 16 + l15;
                bF[ni][kk] = *(const short8*)&rB[r * 64 + ((kk * 4 + q4) ^ (r & 7)) * 8];
            }
        }

        // ---- stage tile t+2 into the free buffer (readers done at t-1) ----
        if (t < 14) stage6q(Ab, Bb, t + 2, sA, sB, tid);

        // ---- 32 MFMA (compiler inserts lgkmcnt before frag use) ----
        __builtin_amdgcn_s_setprio(1);
#pragma unroll
        for (int kk = 0; kk < 2; kk++)
#pragma unroll
            for (int mi = 0; mi < 4; mi++)
#pragma unroll
                for (int ni = 0; ni < 4; ni++)
                    acc[mi][ni] = __builtin_amdgcn_mfma_f32_16x16x32_bf16(
                        aF[mi][kk], bF[ni][kk], acc[mi][ni], 0, 0, 0);
        __builtin_amdgcn_s_setprio(0);

        // ---- drain tile t+1's loads; single barrier per K-tile ----
        if (t < 14)       asm volatile("s_waitcnt vmcnt(6)" ::: "memory");
        else if (t == 14) asm volatile("s_waitcnt vmcnt(0)" ::: "memory");
        if (t < 15) __builtin_amdgcn_s_barrier();

        // rotate: read <- next, next <- stage, stage <- old read
        ushort* ta = rA; rA = nA; nA = sA; sA = ta;
        ushort* tb = rB; rB = nB; nB = sB; sB = tb;
    }

    // C layout: col = lane&15, row = (lane>>4)*4 + r  [m89/m91]
    if (colBase < 2048) {
        // ---- Q/K epilogue: scaled row-major ----
#pragma unroll
        for (int ni = 0; ni < 4; ni++) {
            int col = colBase + wcN + ni * 16 + l15;
            float bv = bias[col];
            int cc = col & 1023;
            ushort* dst = (col < 1024) ? out0 : out1;
#pragma unroll
            for (int mi = 0; mi < 4; mi++) {
                f32x4 a = acc[mi][ni];
#pragma unroll
                for (int r = 0; r < 4; r++) {
                    int row = rowBase + wrM + mi * 16 + q4 * 4 + r;
                    dst[(size_t)row * 1024 + cc] = f2bf((a[r] + bv) * QK_SCALE);
                }
            }
        }
    } else {
        // ---- V epilogue: W[g][d][s7][off], packed 8B stores ----
        int s7 = (colBase - 2048) >> 7;       // 0..7
#pragma unroll
        for (int ni = 0; ni < 4; ni++) {
            int col = colBase + wcN + ni * 16 + l15;
            float bv = bias[col];
            int d = wcN + ni * 16 + l15;      // 0..127
#pragma unroll
            for (int mi = 0; mi < 4; mi++) {
                f32x4 a = acc[mi][ni];
                int row = rowBase + wrM + mi * 16 + q4 * 4;  // 4-pack base
                int g = row >> 7;             // 256-row tile spans 2 heads
                int off0 = row & 127;
                ushort o0 = f2bf(a[0] + bv), o1 = f2bf(a[1] + bv);
                ushort o2 = f2bf(a[2] + bv), o3 = f2bf(a[3] + bv);
                uint2 pk;
                pk.x = (uint)o0 | ((uint)o1 << 16);
                pk.y = (uint)o2 | ((uint)o3 << 16);
                *(uint2*)&wv[(size_t)g * 131072 + (size_t)d * 1024 + s7 * 128 + off0] = pk;
            }
        }
    }
}

// ---------------------------------------------------------------------------
// Out-proj GEMM R18: outf[8192,1024] = A @ woutT^T + bias + resid (fp32 out).
// R15 2-deep structure: 128x128 tile, 256 thr, 64KB LDS, vmcnt(8) pipeline.
// Grid 512 = exactly 2/CU.  XCD x owns M-tiles [8x,8x+8), N-fastest.
// ---------------------------------------------------------------------------
__device__ __forceinline__ void stage8(const ushort* __restrict__ Ab,
                                       const ushort* __restrict__ Bb, int t2,
                                       ushort* AsD, ushort* BsD, int tid) {
    const ushort* As_src = Ab + t2 * 64;
    const ushort* Bs_src = Bb + t2 * 64;
#pragma unroll
    for (int i = 0; i < 4; i++) {
        int lin = i * 256 + tid;             // 0..1023: 16B chunk id of A tile
        int r = lin >> 3, p = lin & 7;
        int l = p ^ (r & 7);
        gload_lds16(As_src + (size_t)r * 1024 + l * 8, &AsD[lin * 8]);
    }
#pragma unroll
    for (int i = 0; i < 4; i++) {
        int lin = i * 256 + tid;             // 0..1023: chunk id of B tile
        int r = lin >> 3, p = lin & 7;
        int l = p ^ (r & 7);
        gload_lds16(Bs_src + (size_t)r * 1024 + l * 8, &BsD[lin * 8]);
    }
}

__global__ __launch_bounds__(256, 2) void gemm_out(
    const ushort* __restrict__ A, const ushort* __restrict__ Bt,
    const float* __restrict__ bias, const ushort* __restrict__ resid,
    float* __restrict__ outf) {
    __shared__ __align__(16) ushort As[2][128 * 64];  // 32 KB
    __shared__ __align__(16) ushort Bs[2][128 * 64];  // 32 KB

    int tid = threadIdx.x;
    int lane = tid & 63, w = tid >> 6;       // 4 waves
    int l15 = lane & 15, q4 = lane >> 4;
    int wrM = (w >> 1) * 64;
    int wcN = (w & 1) * 64;

    int bid = blockIdx.x;
    int xcd = bid & 7;
    int i = bid >> 3;                        // 0..63
    int by = xcd * 8 + (i & 7);              // M-tile 0..63
    int bx = i >> 3;                         // N-tile 0..7
    int rowBase = by * 128, colBase = bx * 128;

    const ushort* Ab = A + (size_t)rowBase * 1024;
    const ushort* Bb = Bt + (size_t)colBase * 1024;

    f32x4 acc[4][4];
    f32x4 zero = {0.f, 0.f, 0.f, 0.f};
#pragma unroll
    for (int mi = 0; mi < 4; mi++)
#pragma unroll
        for (int ni = 0; ni < 4; ni++) acc[mi][ni] = zero;

    stage8(Ab, Bb, 0, &As[0][0], &Bs[0][0], tid);
    stage8(Ab, Bb, 1, &As[1][0], &Bs[1][0], tid);
    asm volatile("s_waitcnt vmcnt(8)" ::: "memory");
    __builtin_amdgcn_s_barrier();

    for (int t = 0; t < 16; ++t) {
        const int cur = t & 1;
        const ushort* Ac = &As[cur][0];
        const ushort* Bc = &Bs[cur][0];

        short8 aF[4][2], bF[4][2];
#pragma unroll
        for (int kk = 0; kk < 2; kk++) {
#pragma unroll
            for (int mi = 0; mi < 4; mi++) {
                int r = wrM + mi * 16 + l15;
                aF[mi][kk] = *(const short8*)&Ac[r * 64 + ((kk * 4 + q4) ^ (r & 7)) * 8];
            }
#pragma unroll
            for (int ni = 0; ni < 4; ni++) {
                int r = wcN + ni * 16 + l15;
                bF[ni][kk] = *(const short8*)&Bc[r * 64 + ((kk * 4 + q4) ^ (r & 7)) * 8];
            }
        }

        __builtin_amdgcn_s_setprio(1);
#pragma unroll
        for (int mi = 0; mi < 4; mi++)
#pragma unroll
            for (int ni = 0; ni < 4; ni++)
                acc[mi][ni] = __builtin_amdgcn_mfma_f32_16x16x32_bf16(
                    aF[mi][0], bF[ni][0], acc[mi][ni], 0, 0, 0);
        __builtin_amdgcn_s_setprio(0);

        asm volatile("s_waitcnt lgkmcnt(0)" ::: "memory");
        __builtin_amdgcn_s_barrier();
        if (t < 14) stage8(Ab, Bb, t + 2, &As[cur][0], &Bs[cur][0], tid);

        __builtin_amdgcn_s_setprio(1);
#pragma unroll
        for (int mi = 0; mi < 4; mi++)
#pragma unroll
            for (int ni = 0; ni < 4; ni++)
                acc[mi][ni] = __builtin_amdgcn_mfma_f32_16x16x32_bf16(
                    aF[mi][1], bF[ni][1], acc[mi][ni], 0, 0, 0);
        __builtin_amdgcn_s_setprio(0);

        if (t < 15) {
            if (t < 14) asm volatile("s_waitcnt vmcnt(8)" ::: "memory");
            else        asm volatile("s_waitcnt vmcnt(0)" ::: "memory");
            __builtin_amdgcn_s_barrier();
        }
    }

#pragma unroll
    for (int ni = 0; ni < 4; ni++) {
        int col = colBase + wcN + ni * 16 + l15;
        float bv = bias[col];
#pragma unroll
        for (int mi = 0; mi < 4; mi++) {
            f32x4 a = acc[mi][ni];
#pragma unroll
            for (int r = 0; r < 4; r++) {
                int row = rowBase + wrM + mi * 16 + q4 * 4 + r;
                outf[(size_t)row * 1024 + col] =
                    a[r] + bv + bf2f(resid[(size_t)row * 1024 + col]);
            }
        }
    }
}

// ---------------------------------------------------------------------------
// Attention R25 (proven): one block = (head g, 256 q-rows); 8 waves; 512 thr.
// KVBLK=128: 8 staging iterations; two identical 64-key halves per iter.
// LDS 160 KB exact: Ks[2][128x128] + Vt[2][128x128] + Ps[256x64].
// 2-deep counted-vmcnt (8 loads/stage -> vmcnt(8)), setprio, W-layout V.
// XCD head-grouping: XCD x owns heads 8x..8x+7 (4 q-blocks each).
// ---------------------------------------------------------------------------
__device__ __forceinline__ void attn_stage(const ushort* __restrict__ Kh,
                                           const ushort* __restrict__ Wg,
                                           int kt, ushort* KsD, ushort* VtD,
                                           int tid) {
    // K: [128 key][128 d], 2048 chunks, XOR-16 within key-row
#pragma unroll
    for (int i = 0; i < 4; i++) {
        int linear = i * 512 + tid;          // 0..2047
        int r = linear >> 4, p = linear & 15;
        int l = p ^ (r & 15);
        gload_lds16(&Kh[(size_t)(kt * 128 + r) * 128 + l * 8], &KsD[linear * 8]);
    }
    // V: [128 d][half 0/1][8 chunks]; phys p: half=p>>3, pl=p&7, cl=pl^(d&7)
#pragma unroll
    for (int i = 0; i < 4; i++) {
        int linear = i * 512 + tid;          // 0..2047
        int d = linear >> 4, p = linear & 15;
        int half = p >> 3, pl = p & 7;
        int cl = pl ^ (d & 7);
        gload_lds16(&Wg[(size_t)d * 1024 + cl * 128 + kt * 16 + half * 8],
                    &VtD[linear * 8]);
    }
}

__global__ __launch_bounds__(512) void attn_kernel(
    const ushort* __restrict__ qb, const ushort* __restrict__ kb,
    const ushort* __restrict__ wv, ushort* __restrict__ ob) {
    // XCD head-grouping: XCD x (bid&7) owns heads 8x..8x+7, 4 q-blocks each.
    int bid = blockIdx.x;
    int xcd = bid & 7, ii = bid >> 3;        // ii 0..31
    int g = xcd * 8 + (ii >> 2);             // head 0..63
    int qblk = ii & 3;                       // 256-row q block
    const ushort* Qh = qb + (size_t)g * 131072;
    const ushort* Kh = kb + (size_t)g * 131072;
    const ushort* Wg = wv + (size_t)g * 131072;  // [128 d][8 s7][128 off]

    __shared__ __align__(16) ushort Ks[2][128 * 128];  // 64 KB
    __shared__ __align__(16) ushort Vt[2][128 * 128];  // 64 KB
    __shared__ __align__(16) ushort Ps[256 * 64];      // 32 KB

    int tid = threadIdx.x, lane = tid & 63, w = tid >> 6;  // w in [0,8)
    int l15 = lane & 15, q4 = lane >> 4;
    int q0 = qblk * 256;

    // Q A-fragments for 2 sub-blocks: rows q0 + w*32 + sub*16 + l15
    short8 qf[2][4];
#pragma unroll
    for (int sub = 0; sub < 2; sub++)
#pragma unroll
        for (int ks = 0; ks < 4; ks++)
            qf[sub][ks] = *(const short8*)&Qh[
                (size_t)(q0 + w * 32 + sub * 16 + l15) * 128 + ks * 32 + q4 * 8];

    f32x4 zero = {0.f, 0.f, 0.f, 0.f};
    f32x4 o[2][8];
#pragma unroll
    for (int sub = 0; sub < 2; sub++)
#pragma unroll
        for (int ni = 0; ni < 8; ni++) o[sub][ni] = zero;
    float plsum[2][4] = {{0.f, 0.f, 0.f, 0.f}, {0.f, 0.f, 0.f, 0.f}};

    // prologue: stage kt0 -> buf0, kt1 -> buf1; wait only kt0 (8 left)
    attn_stage(Kh, Wg, 0, &Ks[0][0], &Vt[0][0], tid);
    attn_stage(Kh, Wg, 1, &Ks[1][0], &Vt[1][0], tid);
    asm volatile("s_waitcnt vmcnt(8)" ::: "memory");
    __builtin_amdgcn_s_barrier();

    for (int kt = 0; kt < 8; kt++) {
        const int cur = kt & 1;
        const ushort* Kc = &Ks[cur][0];
        const ushort* Vc = &Vt[cur][0];

        // two identical 64-key halves (keys h*64 .. h*64+63 of this tile)
#pragma unroll
        for (int h = 0; h < 2; h++) {
            // S = Q K^T : 32q x 64key per wave; K frag shared across subs
            f32x4 sacc[2][4];
#pragma unroll
            for (int sub = 0; sub < 2; sub++)
#pragma unroll
                for (int ni = 0; ni < 4; ni++) sacc[sub][ni] = zero;
            __builtin_amdgcn_s_setprio(1);
#pragma unroll
            for (int ks = 0; ks < 4; ks++) {
#pragma unroll
                for (int ni = 0; ni < 4; ni++) {
                    int r = h * 64 + ni * 16 + l15;
                    int p = (ks * 4 + q4) ^ (r & 15);
                    short8 bF = *(const short8*)&Kc[r * 128 + p * 8];
#pragma unroll
                    for (int sub = 0; sub < 2; sub++)
                        sacc[sub][ni] = __builtin_amdgcn_mfma_f32_16x16x32_bf16(
                            qf[sub][ks], bF, sacc[sub][ni], 0, 0, 0);
                }
            }
            __builtin_amdgcn_s_setprio(0);

            // P = exp(S) -> Ps at slot (key&7)*8+(key>>3) (W chunk semantics)
#pragma unroll
            for (int sub = 0; sub < 2; sub++)
#pragma unroll
                for (int ni = 0; ni < 4; ni++) {
#pragma unroll
                    for (int r = 0; r < 4; r++) {
                        float pv = __expf(sacc[sub][ni][r]);
                        plsum[sub][r] += pv;
                        int qloc = w * 32 + sub * 16 + q4 * 4 + r;  // wave-priv
                        int key = ni * 16 + l15;
                        int pc = (key & 7) ^ (qloc & 7);
                        Ps[qloc * 64 + pc * 8 + (key >> 3)] = f2bf(pv);
                    }
                }

            // O += P V  (V frag shared across subs; half-offset h*64 keys)
            __builtin_amdgcn_s_setprio(1);
#pragma unroll
            for (int ks2 = 0; ks2 < 2; ks2++) {
                int c = ks2 * 4 + q4;
                short8 aF[2];
#pragma unroll
                for (int sub = 0; sub < 2; sub++) {
                    int row = w * 32 + sub * 16 + l15;        // row&7 == l15&7
                    aF[sub] = *(const short8*)&Ps[row * 64 + (c ^ (l15 & 7)) * 8];
                }
#pragma unroll
                for (int ni = 0; ni < 8; ni++) {
                    int d = ni * 16 + l15;
                    short8 bF = *(const short8*)&Vc[d * 128 + h * 64 + (c ^ (d & 7)) * 8];
#pragma unroll
                    for (int sub = 0; sub < 2; sub++)
                        o[sub][ni] = __builtin_amdgcn_mfma_f32_16x16x32_bf16(
                            aF[sub], bF, o[sub][ni], 0, 0, 0);
                }
            }
            __builtin_amdgcn_s_setprio(0);
        }

        // ---- all LDS reads of buf[cur] done -> restage; counted vmcnt ----
        asm volatile("s_waitcnt lgkmcnt(0)" ::: "memory");
        __builtin_amdgcn_s_barrier();
        if (kt < 6) attn_stage(Kh, Wg, kt + 2, &Ks[cur][0], &Vt[cur][0], tid);
        if (kt < 6)       asm volatile("s_waitcnt vmcnt(8)" ::: "memory");
        else if (kt == 6) asm volatile("s_waitcnt vmcnt(0)" ::: "memory");
        if (kt < 7) __builtin_amdgcn_s_barrier();
    }

    // row sums: reduce per-lane partials over the 16 l15-lanes
#pragma unroll
    for (int sub = 0; sub < 2; sub++)
#pragma unroll
        for (int r = 0; r < 4; r++) {
#pragma unroll
            for (int m = 1; m < 16; m <<= 1)
                plsum[sub][r] += __shfl_xor(plsum[sub][r], m, 16);
        }
#pragma unroll
    for (int sub = 0; sub < 2; sub++) {
        float inv[4];
#pragma unroll
        for (int r = 0; r < 4; r++) inv[r] = 1.0f / plsum[sub][r];
#pragma unroll
        for (int ni = 0; ni < 8; ni++)
#pragma unroll
            for (int r = 0; r < 4; r++) {
                int qrow = q0 + w * 32 + sub * 16 + q4 * 4 + r;
                ob[(size_t)g * 131072 + (size_t)qrow * 128 + ni * 16 + l15] =
                    f2bf(o[sub][ni][r] * inv[r]);
            }
    }
}

// ---------------------------------------------------------------------------
extern "C" void kernel_launch(void* const* d_in, const int* in_sizes, int n_in,
                              void* d_out, int out_size, void* d_ws, size_t ws_size,
                              hipStream_t stream) {
    const float* x     = (const float*)d_in[0];
    const float* ln_g  = (const float*)d_in[1];
    const float* ln_b  = (const float*)d_in[2];
    const float* w_qkv = (const float*)d_in[3];
    const float* b_qkv = (const float*)d_in[4];
    const float* w_out = (const float*)d_in[5];
    const float* b_out = (const float*)d_in[6];
    float* out = (float*)d_out;

    const size_t MC = 8192ull * 1024ull;  // 8.39M elems
    ushort* xn    = (ushort*)d_ws;
    ushort* wqkvT = xn + MC;
    ushort* woutT = wqkvT + 3072ull * 1024ull;
    ushort* qbuf  = woutT + 1024ull * 1024ull;
    ushort* kbuf  = qbuf + MC;
    ushort* vtbuf = kbuf + MC;        // W: V in [g][d][s7][off] layout
    ushort* attnb = vtbuf + MC;       // attn output
    // total: 46.14M ushorts = 92.3 MB (same layout as passing rounds)

    prep_kernel<<<6144, 256, 0, stream>>>(x, ln_g, ln_b, xn, w_qkv, wqkvT, w_out, woutT);
    // q,k -> qbuf,kbuf ; v -> vtbuf in W layout (transpose_head eliminated)
    gemm_qkv<<<768, 512, 0, stream>>>(xn, wqkvT, b_qkv, qbuf, kbuf, vtbuf);
    attn_kernel<<<256, 512, 0, stream>>>(qbuf, kbuf, vtbuf, attnb);
    gemm_out<<<512, 256, 0, stream>>>(attnb, woutT, b_out, xn, out);
}